// Round 7
// baseline (372.539 us; speedup 1.0000x reference)
//
#include <hip/hip_runtime.h>
#include <hip/hip_bf16.h>
#include <math.h>

#define N_TOK 8192
#define D_IN  1024
#define D_H   128
#define SPLIT 12

typedef __bf16 bf16;
typedef __attribute__((ext_vector_type(4))) __bf16 bf16x4;
typedef __attribute__((ext_vector_type(8))) __bf16 bf16x8;
typedef __attribute__((ext_vector_type(4))) float floatx4;

#define MFMA16(a, b, c) __builtin_amdgcn_mfma_f32_16x16x32_bf16((a), (b), (c), 0, 0, 0)

// V fragment order (B-operand for PV): [ntile][ct][lane][j]
__device__ __forceinline__ size_t vtf_idx(int n, int d) {
    return ((size_t)((n >> 6) * 8 + (d >> 4)) << 10)
         + (((n >> 3) & 7) << 7) + ((d & 15) << 3) + (n & 7);
}
// K fragment order (B-operand for QK^T): [ktile][kc][ct][lane][j]
__device__ __forceinline__ size_t khf_idx(int n, int d) {
    return ((size_t)(((n >> 6) * 4 + (d >> 5)) * 4 + ((n >> 4) & 3)) << 9)
         + (((d >> 3) & 3) << 7) + ((n & 15) << 3) + (d & 7);
}

#define X_OCT (N_TOK * D_IN / 8)        // 1048576 fragment-octets of x
#define W_OCT (3 * D_H * D_IN / 8)      // 49152 fragment-octets of W

// ---------------------------------------------------------------------------
// Kernel 0: one-time fp32 -> split-bf16 conversion into MFMA fragment order.
//   x  -> xhf/xlf, A-operand order:  [mtile][kc][lane][j]
//   Wy -> whf/wlf, B-operand order:  [y][ctile][kc][lane][j]
// One thread = one 8-element fragment octet: 2 float4 reads, bf16x8 x2 writes.
// ---------------------------------------------------------------------------
__global__ __launch_bounds__(256)
void convert_kernel(const float* __restrict__ x,
                    const float* __restrict__ Wq,
                    const float* __restrict__ Wk,
                    const float* __restrict__ Wv,
                    bf16* __restrict__ xhf, bf16* __restrict__ xlf,
                    bf16* __restrict__ whf, bf16* __restrict__ wlf)
{
    const int gid = blockIdx.x * 256 + threadIdx.x;
    const float* src;
    bf16 *dh, *dl;
    size_t doff;
    if (gid < X_OCT) {
        int lane = gid & 63, fc = gid >> 6;
        int kc = fc & 31, mt = fc >> 5;
        int n  = mt * 16 + (lane & 15);
        int k0 = kc * 32 + ((lane >> 4) << 3);
        src = x + (size_t)n * D_IN + k0;
        dh = xhf; dl = xlf; doff = (size_t)gid << 3;
    } else {
        int w = gid - X_OCT;              // [0, 49152)
        int y = w >> 14, r = w & 16383;   // 16384 octets per matrix
        int lane = r & 63, fc = r >> 6;
        int kc = fc & 31, ct = fc >> 5;
        int col = ct * 16 + (lane & 15);
        int k0  = kc * 32 + ((lane >> 4) << 3);
        const float* W = (y == 0) ? Wq : (y == 1) ? Wk : Wv;
        src = W + (size_t)col * D_IN + k0;
        dh = whf; dl = wlf; doff = (size_t)w << 3;
    }
    float4 a = *(const float4*)src;
    float4 b = *(const float4*)(src + 4);
    float vv[8] = { a.x, a.y, a.z, a.w, b.x, b.y, b.z, b.w };
    bf16x8 h, l;
    #pragma unroll
    for (int j = 0; j < 8; ++j) {
        bf16 hh = (bf16)vv[j];
        h[j] = hh;
        l[j] = (bf16)(vv[j] - (float)hh);
    }
    *(bf16x8*)(dh + doff) = h;
    *(bf16x8*)(dl + doff) = l;
}

// ---------------------------------------------------------------------------
// Kernel 1: QKV projection GEMM, split-bf16 3-pass MFMA, ZERO LDS/barriers.
// grid (128, 3), block 256 = 4 waves in 2x2 (wave = 32 rows x 64 cols).
// A/B fragments read DIRECT from global in fragment order (coalesced 1 KB
// per instruction; W slice is 0.5 MB -> L2-hot across all 128 x-blocks).
// Epilogue: y=0 -> qh/ql row-major (sqrt(128) folded); y=1 -> khf/klf frag
// order; y=2 -> vtf frag order.
// ---------------------------------------------------------------------------
__global__ __launch_bounds__(256)
void qkv_kernel(const bf16* __restrict__ xhf, const bf16* __restrict__ xlf,
                const bf16* __restrict__ whf, const bf16* __restrict__ wlf,
                bf16* __restrict__ q_hi, bf16* __restrict__ q_lo,
                bf16* __restrict__ khf, bf16* __restrict__ klf,
                bf16* __restrict__ vtf)
{
    const int t    = threadIdx.x;
    const int lane = t & 63;
    const int wid  = t >> 6;
    const int wr   = wid >> 1;
    const int wc   = wid & 1;
    const int lid  = lane & 15;
    const int quad = lane >> 4;
    const int m0   = blockIdx.x * 64;
    const int mt0  = (m0 >> 4) + wr * 2;      // wave's first mtile
    const bf16* wh = whf + ((size_t)blockIdx.y << 17);   // 131072 elems per y
    const bf16* wl = wlf + ((size_t)blockIdx.y << 17);

    floatx4 acc[2][4];
    #pragma unroll
    for (int m = 0; m < 2; ++m)
        #pragma unroll
        for (int ct = 0; ct < 4; ++ct)
            #pragma unroll
            for (int r = 0; r < 4; ++r) acc[m][ct][r] = 0.f;

    #pragma unroll 4
    for (int kc = 0; kc < 32; ++kc) {
        bf16x8 ah[2], al[2];
        #pragma unroll
        for (int m = 0; m < 2; ++m) {
            const size_t xb = ((size_t)((mt0 + m) * 32 + kc) << 9) + (lane << 3);
            ah[m] = *(const bf16x8*)(xhf + xb);
            al[m] = *(const bf16x8*)(xlf + xb);
        }
        #pragma unroll
        for (int ct = 0; ct < 4; ++ct) {
            const size_t wb = ((size_t)((wc * 4 + ct) * 32 + kc) << 9) + (lane << 3);
            bf16x8 bh = *(const bf16x8*)(wh + wb);
            bf16x8 bl = *(const bf16x8*)(wl + wb);
            #pragma unroll
            for (int m = 0; m < 2; ++m) {
                acc[m][ct] = MFMA16(ah[m], bh, acc[m][ct]);
                acc[m][ct] = MFMA16(al[m], bh, acc[m][ct]);
                acc[m][ct] = MFMA16(ah[m], bl, acc[m][ct]);
            }
        }
    }

    if (blockIdx.y == 0) {
        const float sc = 11.313708498984760390f;
        #pragma unroll
        for (int s2 = 0; s2 < 2; ++s2)
            #pragma unroll
            for (int ct = 0; ct < 4; ++ct)
                #pragma unroll
                for (int r = 0; r < 4; ++r) {
                    int row = m0 + wr * 32 + s2 * 16 + quad * 4 + r;
                    int col = wc * 64 + ct * 16 + lid;
                    float a = acc[s2][ct][r] * sc;
                    bf16 h = (bf16)a;
                    q_hi[(size_t)row * D_H + col] = h;
                    q_lo[(size_t)row * D_H + col] = (bf16)(a - (float)h);
                }
    } else if (blockIdx.y == 1) {
        #pragma unroll
        for (int s2 = 0; s2 < 2; ++s2)
            #pragma unroll
            for (int ct = 0; ct < 4; ++ct)
                #pragma unroll
                for (int r = 0; r < 4; ++r) {
                    int n = m0 + wr * 32 + s2 * 16 + quad * 4 + r;
                    int d = wc * 64 + ct * 16 + lid;
                    float a = acc[s2][ct][r];
                    bf16 h = (bf16)a;
                    size_t idx = khf_idx(n, d);
                    khf[idx] = h;
                    klf[idx] = (bf16)(a - (float)h);
                }
    } else {
        #pragma unroll
        for (int s2 = 0; s2 < 2; ++s2)
            #pragma unroll
            for (int ct = 0; ct < 4; ++ct)
                #pragma unroll
                for (int r = 0; r < 4; ++r) {
                    int n = m0 + wr * 32 + s2 * 16 + quad * 4 + r;
                    int d = wc * 64 + ct * 16 + lid;
                    vtf[vtf_idx(n, d)] = (bf16)acc[s2][ct][r];
                }
    }
}

// ---------------------------------------------------------------------------
// Kernel 2: flash attention. BQ=128/block (4 waves x 32 q-rows), BKEY=64,
// SPLIT=12 -> grid (64,12)=768 = 3 blocks/CU (LDS 48 KB, VGPR 128 <= 170).
// Structure identical to round 6; only SPLIT and launch_bounds changed.
// ---------------------------------------------------------------------------
#define BQ   128
#define BKEY 64

__global__ __launch_bounds__(256, 3)
void flash_kernel(const bf16* __restrict__ qh, const bf16* __restrict__ ql,
                  const bf16* __restrict__ khf, const bf16* __restrict__ klf,
                  const bf16* __restrict__ vtf,
                  bf16*  __restrict__ opart,   // [SPLIT][N][D_H] unnormalized
                  float* __restrict__ mpart,   // [SPLIT][N]
                  float* __restrict__ lpart)   // [SPLIT][N]
{
    __shared__ bf16 kh_s[BKEY * D_H];     // fragment order, 16 KB
    __shared__ bf16 kl_s[BKEY * D_H];     // 16 KB
    __shared__ bf16 p_s[4 * 2048];        // per-wave A-frag P, 16 KB

    const int t     = threadIdx.x;
    const int lane  = t & 63;
    const int wid   = t >> 6;
    const int lid   = lane & 15;
    const int quad  = lane >> 4;
    const int q0    = blockIdx.x * BQ;
    const int strip = wid * 32;
    const int sp    = blockIdx.y;
    const int tile0 = (sp * (N_TOK / BKEY)) / SPLIT;        // balanced split
    const int tile1 = ((sp + 1) * (N_TOK / BKEY)) / SPLIT;

    bf16x8 a_hi[2][4], a_lo[2][4];
    #pragma unroll
    for (int m = 0; m < 2; ++m) {
        const size_t rowb = (size_t)(q0 + strip + m * 16 + lid) * D_H + quad * 8;
        #pragma unroll
        for (int kc = 0; kc < 4; ++kc) {
            a_hi[m][kc] = *(const bf16x8*)(qh + rowb + kc * 32);
            a_lo[m][kc] = *(const bf16x8*)(ql + rowb + kc * 32);
        }
    }

    bf16x8 vones;
    #pragma unroll
    for (int j = 0; j < 8; ++j) vones[j] = (bf16)1.0f;

    float m_run[2][4];
    #pragma unroll
    for (int m = 0; m < 2; ++m)
        #pragma unroll
        for (int r = 0; r < 4; ++r) m_run[m][r] = -INFINITY;
    floatx4 l_acc[2];
    #pragma unroll
    for (int m = 0; m < 2; ++m)
        #pragma unroll
        for (int r = 0; r < 4; ++r) l_acc[m][r] = 0.f;
    floatx4 o_acc[2][8];
    #pragma unroll
    for (int m = 0; m < 2; ++m)
        #pragma unroll
        for (int ct = 0; ct < 8; ++ct)
            #pragma unroll
            for (int r = 0; r < 4; ++r) o_acc[m][ct][r] = 0.f;

    auto stage = [&](int tile) {
        const bf16* gh = khf + ((size_t)tile << 13) + (wid << 11) + (lane << 3);
        const bf16* gl = klf + ((size_t)tile << 13) + (wid << 11) + (lane << 3);
        bf16* lh = kh_s + (wid << 11);
        bf16* ll = kl_s + (wid << 11);
        #pragma unroll
        for (int i = 0; i < 4; ++i) {
            __builtin_amdgcn_global_load_lds(
                (const __attribute__((address_space(1))) void*)(gh + i * 512),
                (__attribute__((address_space(3))) void*)(lh + i * 512), 16, 0, 0);
            __builtin_amdgcn_global_load_lds(
                (const __attribute__((address_space(1))) void*)(gl + i * 512),
                (__attribute__((address_space(3))) void*)(ll + i * 512), 16, 0, 0);
        }
    };

    stage(tile0);

    for (int tt = tile0; tt < tile1; ++tt) {
        __syncthreads();

        floatx4 s[2][4];
        #pragma unroll
        for (int m = 0; m < 2; ++m)
            #pragma unroll
            for (int ct = 0; ct < 4; ++ct)
                #pragma unroll
                for (int r = 0; r < 4; ++r) s[m][ct][r] = 0.f;

        #pragma unroll
        for (int kc = 0; kc < 4; ++kc)
            #pragma unroll
            for (int ct = 0; ct < 4; ++ct) {
                const int fo = ((kc * 4 + ct) << 9) + (lane << 3);
                bf16x8 bh = *(const bf16x8*)&kh_s[fo];
                bf16x8 bl = *(const bf16x8*)&kl_s[fo];
                #pragma unroll
                for (int m = 0; m < 2; ++m) {
                    s[m][ct] = MFMA16(a_hi[m][kc], bh, s[m][ct]);
                    s[m][ct] = MFMA16(a_lo[m][kc], bh, s[m][ct]);
                    s[m][ct] = MFMA16(a_hi[m][kc], bl, s[m][ct]);
                }
            }

        __syncthreads();
        if (tt + 1 < tile1) stage(tt + 1);

        const bf16* vb = vtf + (((size_t)tt * 8) << 10) + (lane << 3);
        bf16x8 bv0[8];
        #pragma unroll
        for (int ct = 0; ct < 8; ++ct)
            bv0[ct] = *(const bf16x8*)(vb + ((size_t)ct << 10));

        float alpha[2][4];
        #pragma unroll
        for (int m = 0; m < 2; ++m)
            #pragma unroll
            for (int r = 0; r < 4; ++r) {
                float mx = fmaxf(fmaxf(s[m][0][r], s[m][1][r]),
                                 fmaxf(s[m][2][r], s[m][3][r]));
                #pragma unroll
                for (int off = 1; off < 16; off <<= 1)
                    mx = fmaxf(mx, __shfl_xor(mx, off, 64));
                float mn = fmaxf(m_run[m][r], mx);
                alpha[m][r] = __expf(m_run[m][r] - mn);
                m_run[m][r] = mn;
                #pragma unroll
                for (int ct = 0; ct < 4; ++ct) {
                    float p = __expf(s[m][ct][r] - mn);
                    int fl = (((m * 2 + (ct >> 1)) << 6)
                              + (((ct & 1) * 2 + (lid >> 3)) << 4)
                              + quad * 4 + r) * 8 + (lid & 7);
                    p_s[(wid << 11) + fl] = (bf16)p;
                }
            }

        bool need = false;
        #pragma unroll
        for (int m = 0; m < 2; ++m)
            #pragma unroll
            for (int r = 0; r < 4; ++r) need |= (alpha[m][r] != 1.0f);
        if (__any(need)) {
            #pragma unroll
            for (int m = 0; m < 2; ++m) {
                #pragma unroll
                for (int r = 0; r < 4; ++r) l_acc[m][r] *= alpha[m][r];
                #pragma unroll
                for (int ct = 0; ct < 8; ++ct)
                    #pragma unroll
                    for (int r = 0; r < 4; ++r)
                        o_acc[m][ct][r] *= alpha[m][r];
            }
        }

        {
            bf16x8 ap0[2];
            #pragma unroll
            for (int m = 0; m < 2; ++m)
                ap0[m] = *(const bf16x8*)&p_s[(wid << 11) + (((m * 2 + 0) << 6) << 3)
                                              + (lane << 3)];
            #pragma unroll
            for (int m = 0; m < 2; ++m)
                l_acc[m] = MFMA16(ap0[m], vones, l_acc[m]);
            #pragma unroll
            for (int ct = 0; ct < 8; ++ct)
                #pragma unroll
                for (int m = 0; m < 2; ++m)
                    o_acc[m][ct] = MFMA16(ap0[m], bv0[ct], o_acc[m][ct]);

            bf16x8 bv1[8];
            #pragma unroll
            for (int ct = 0; ct < 8; ++ct)
                bv1[ct] = *(const bf16x8*)(vb + ((size_t)ct << 10) + 512);
            bf16x8 ap1[2];
            #pragma unroll
            for (int m = 0; m < 2; ++m)
                ap1[m] = *(const bf16x8*)&p_s[(wid << 11) + (((m * 2 + 1) << 6) << 3)
                                              + (lane << 3)];
            #pragma unroll
            for (int m = 0; m < 2; ++m)
                l_acc[m] = MFMA16(ap1[m], vones, l_acc[m]);
            #pragma unroll
            for (int ct = 0; ct < 8; ++ct)
                #pragma unroll
                for (int m = 0; m < 2; ++m)
                    o_acc[m][ct] = MFMA16(ap1[m], bv1[ct], o_acc[m][ct]);
        }
    }

    bf16* op = opart + (size_t)sp * N_TOK * D_H;
    #pragma unroll
    for (int m = 0; m < 2; ++m)
        #pragma unroll
        for (int ct = 0; ct < 8; ++ct)
            #pragma unroll
            for (int r = 0; r < 4; ++r)
                op[(size_t)(q0 + strip + m * 16 + quad * 4 + r) * D_H
                   + ct * 16 + lid] = (bf16)o_acc[m][ct][r];
    if (lid == 0) {
        #pragma unroll
        for (int m = 0; m < 2; ++m)
            #pragma unroll
            for (int r = 0; r < 4; ++r) {
                int row = q0 + strip + m * 16 + quad * 4 + r;
                mpart[(size_t)sp * N_TOK + row] = m_run[m][r];
                lpart[(size_t)sp * N_TOK + row] = l_acc[m][r];
            }
    }
}

// ---------------------------------------------------------------------------
// Kernel 3: merge the SPLIT partials.
// ---------------------------------------------------------------------------
__global__ __launch_bounds__(256)
void combine_kernel(const bf16* __restrict__ opart,
                    const float* __restrict__ mpart,
                    const float* __restrict__ lpart,
                    float* __restrict__ out)
{
    const int t   = threadIdx.x;
    const int row = blockIdx.x * 16 + (t >> 4);
    const int c0  = (t & 15) * 8;

    float ms[SPLIT], ls[SPLIT];
    float mstar = -INFINITY;
    #pragma unroll
    for (int s = 0; s < SPLIT; ++s) {
        ms[s] = mpart[(size_t)s * N_TOK + row];
        ls[s] = lpart[(size_t)s * N_TOK + row];
        mstar = fmaxf(mstar, ms[s]);
    }
    float acc[8] = {};
    float L = 0.f;
    #pragma unroll
    for (int s = 0; s < SPLIT; ++s) {
        float w = __expf(ms[s] - mstar);
        L += w * ls[s];
        bf16x8 o = *(const bf16x8*)&opart[((size_t)s * N_TOK + row) * D_H + c0];
        #pragma unroll
        for (int j = 0; j < 8; ++j)
            acc[j] += w * (float)o[j];
    }
    float inv = 1.f / L;
    float* dst = &out[(size_t)row * D_H + c0];
    *(float4*)(dst + 0) = make_float4(acc[0] * inv, acc[1] * inv,
                                      acc[2] * inv, acc[3] * inv);
    *(float4*)(dst + 4) = make_float4(acc[4] * inv, acc[5] * inv,
                                      acc[6] * inv, acc[7] * inv);
}

// ---------------------------------------------------------------------------
extern "C" void kernel_launch(void* const* d_in, const int* in_sizes, int n_in,
                              void* d_out, int out_size, void* d_ws, size_t ws_size,
                              hipStream_t stream) {
    const float* x  = (const float*)d_in[0];
    const float* Wq = (const float*)d_in[1];
    const float* Wk = (const float*)d_in[2];
    const float* Wv = (const float*)d_in[3];
    float* out = (float*)d_out;

    // ws (bf16): xhf/xlf (8.4M each), whf/wlf (393K each), qh/ql/khf/klf/vtf
    //            (1.05M each), opart [12][N][128]; fp32 mpart/lpart [12][N].
    //            Total ~72 MB.
    bf16* wsb = (bf16*)d_ws;
    const size_t SZ = (size_t)N_TOK * D_H;          // 1048576
    bf16* xhf = wsb;
    bf16* xlf = xhf + (size_t)X_OCT * 8;
    bf16* whf = xlf + (size_t)X_OCT * 8;
    bf16* wlf = whf + (size_t)W_OCT * 8;
    bf16* qh  = wlf + (size_t)W_OCT * 8;
    bf16* ql  = qh + SZ;
    bf16* khf = ql + SZ;
    bf16* klf = khf + SZ;
    bf16* vtf = klf + SZ;
    bf16* opart = vtf + SZ;
    float* mpart = (float*)(opart + (size_t)SPLIT * SZ);
    float* lpart = mpart + (size_t)SPLIT * N_TOK;

    convert_kernel<<<dim3((X_OCT + W_OCT) / 256), 256, 0, stream>>>(
        x, Wq, Wk, Wv, xhf, xlf, whf, wlf);
    qkv_kernel<<<dim3(N_TOK / 64, 3), 256, 0, stream>>>(
        xhf, xlf, whf, wlf, qh, ql, khf, klf, vtf);
    flash_kernel<<<dim3(N_TOK / BQ, SPLIT), 256, 0, stream>>>(
        qh, ql, khf, klf, vtf, opart, mpart, lpart);
    combine_kernel<<<dim3(N_TOK / 16), 256, 0, stream>>>(opart, mpart, lpart, out);
}

// Round 8
// 230.057 us; speedup vs baseline: 1.6193x; 1.6193x over previous
//
#include <hip/hip_runtime.h>
#include <hip/hip_bf16.h>
#include <math.h>

#define N_TOK 8192
#define D_IN  1024
#define D_H   128
#define SPLIT 8

typedef __bf16 bf16;
typedef __attribute__((ext_vector_type(4))) __bf16 bf16x4;
typedef __attribute__((ext_vector_type(8))) __bf16 bf16x8;
typedef __attribute__((ext_vector_type(4))) float floatx4;

#define MFMA16(a, b, c) __builtin_amdgcn_mfma_f32_16x16x32_bf16((a), (b), (c), 0, 0, 0)

// V fragment order (B-operand for PV): [ntile][ct][lane][j]
__device__ __forceinline__ size_t vtf_idx(int n, int d) {
    return ((size_t)((n >> 6) * 8 + (d >> 4)) << 10)
         + (((n >> 3) & 7) << 7) + ((d & 15) << 3) + (n & 7);
}
// K fragment order (B-operand for QK^T): [ktile][kc][ct][lane][j]
__device__ __forceinline__ size_t khf_idx(int n, int d) {
    return ((size_t)(((n >> 6) * 4 + (d >> 5)) * 4 + ((n >> 4) & 3)) << 9)
         + (((d >> 3) & 3) << 7) + ((n & 15) << 3) + (d & 7);
}

#define X_OCT (N_TOK * D_IN / 8)        // 1048576 fragment-octets of x
#define W_OCT (3 * D_H * D_IN / 8)      // 49152 fragment-octets of W

// ---------------------------------------------------------------------------
// Kernel 0: one-time fp32 -> split-bf16 conversion into MFMA fragment order.
// ---------------------------------------------------------------------------
__global__ __launch_bounds__(256)
void convert_kernel(const float* __restrict__ x,
                    const float* __restrict__ Wq,
                    const float* __restrict__ Wk,
                    const float* __restrict__ Wv,
                    bf16* __restrict__ xhf, bf16* __restrict__ xlf,
                    bf16* __restrict__ whf, bf16* __restrict__ wlf)
{
    const int gid = blockIdx.x * 256 + threadIdx.x;
    const float* src;
    bf16 *dh, *dl;
    size_t doff;
    if (gid < X_OCT) {
        int lane = gid & 63, fc = gid >> 6;
        int kc = fc & 31, mt = fc >> 5;
        int n  = mt * 16 + (lane & 15);
        int k0 = kc * 32 + ((lane >> 4) << 3);
        src = x + (size_t)n * D_IN + k0;
        dh = xhf; dl = xlf; doff = (size_t)gid << 3;
    } else {
        int w = gid - X_OCT;
        int y = w >> 14, r = w & 16383;
        int lane = r & 63, fc = r >> 6;
        int kc = fc & 31, ct = fc >> 5;
        int col = ct * 16 + (lane & 15);
        int k0  = kc * 32 + ((lane >> 4) << 3);
        const float* W = (y == 0) ? Wq : (y == 1) ? Wk : Wv;
        src = W + (size_t)col * D_IN + k0;
        dh = whf; dl = wlf; doff = (size_t)w << 3;
    }
    float4 a = *(const float4*)src;
    float4 b = *(const float4*)(src + 4);
    float vv[8] = { a.x, a.y, a.z, a.w, b.x, b.y, b.z, b.w };
    bf16x8 h, l;
    #pragma unroll
    for (int j = 0; j < 8; ++j) {
        bf16 hh = (bf16)vv[j];
        h[j] = hh;
        l[j] = (bf16)(vv[j] - (float)hh);
    }
    *(bf16x8*)(dh + doff) = h;
    *(bf16x8*)(dl + doff) = l;
}

// ---------------------------------------------------------------------------
// Kernel 1: QKV projection GEMM, split-bf16 3-pass MFMA, zero LDS/barriers.
// BM=32 -> grid (256, 3) = 768 blocks = 3 blocks/CU (12 waves/CU hides L2
// latency on the direct-from-global fragment reads). Wave (wr,wc) computes
// 16 rows x 64 cols.
// ---------------------------------------------------------------------------
__global__ __launch_bounds__(256)
void qkv_kernel(const bf16* __restrict__ xhf, const bf16* __restrict__ xlf,
                const bf16* __restrict__ whf, const bf16* __restrict__ wlf,
                bf16* __restrict__ q_hi, bf16* __restrict__ q_lo,
                bf16* __restrict__ khf, bf16* __restrict__ klf,
                bf16* __restrict__ vtf)
{
    const int t    = threadIdx.x;
    const int lane = t & 63;
    const int wid  = t >> 6;
    const int wr   = wid >> 1;
    const int wc   = wid & 1;
    const int lid  = lane & 15;
    const int quad = lane >> 4;
    const int m0   = blockIdx.x * 32;
    const int mt   = blockIdx.x * 2 + wr;     // wave's mtile
    const bf16* wh = whf + ((size_t)blockIdx.y << 17);
    const bf16* wl = wlf + ((size_t)blockIdx.y << 17);

    floatx4 acc[4];
    #pragma unroll
    for (int ct = 0; ct < 4; ++ct)
        #pragma unroll
        for (int r = 0; r < 4; ++r) acc[ct][r] = 0.f;

    #pragma unroll 4
    for (int kc = 0; kc < 32; ++kc) {
        const size_t xb = ((size_t)(mt * 32 + kc) << 9) + (lane << 3);
        bf16x8 ah = *(const bf16x8*)(xhf + xb);
        bf16x8 al = *(const bf16x8*)(xlf + xb);
        #pragma unroll
        for (int ct = 0; ct < 4; ++ct) {
            const size_t wb = ((size_t)((wc * 4 + ct) * 32 + kc) << 9) + (lane << 3);
            bf16x8 bh = *(const bf16x8*)(wh + wb);
            bf16x8 bl = *(const bf16x8*)(wl + wb);
            acc[ct] = MFMA16(ah, bh, acc[ct]);
            acc[ct] = MFMA16(al, bh, acc[ct]);
            acc[ct] = MFMA16(ah, bl, acc[ct]);
        }
    }

    if (blockIdx.y == 0) {
        const float sc = 11.313708498984760390f;
        #pragma unroll
        for (int ct = 0; ct < 4; ++ct)
            #pragma unroll
            for (int r = 0; r < 4; ++r) {
                int row = m0 + wr * 16 + quad * 4 + r;
                int col = wc * 64 + ct * 16 + lid;
                float a = acc[ct][r] * sc;
                bf16 h = (bf16)a;
                q_hi[(size_t)row * D_H + col] = h;
                q_lo[(size_t)row * D_H + col] = (bf16)(a - (float)h);
            }
    } else if (blockIdx.y == 1) {
        #pragma unroll
        for (int ct = 0; ct < 4; ++ct)
            #pragma unroll
            for (int r = 0; r < 4; ++r) {
                int n = m0 + wr * 16 + quad * 4 + r;
                int d = wc * 64 + ct * 16 + lid;
                float a = acc[ct][r];
                bf16 h = (bf16)a;
                size_t idx = khf_idx(n, d);
                khf[idx] = h;
                klf[idx] = (bf16)(a - (float)h);
            }
    } else {
        #pragma unroll
        for (int ct = 0; ct < 4; ++ct)
            #pragma unroll
            for (int r = 0; r < 4; ++r) {
                int n = m0 + wr * 16 + quad * 4 + r;
                int d = wc * 64 + ct * 16 + lid;
                vtf[vtf_idx(n, d)] = (bf16)acc[ct][r];
            }
    }
}

// ---------------------------------------------------------------------------
// Kernel 2: flash attention. BQ=128 (4 waves x 32 q-rows), BKEY=64,
// SPLIT=8 -> grid (64,8)=512 = 2 blocks/CU (register capacity; LDS 64 KB).
// K AND V staged to LDS via async global_load_lds (V was previously read
// redundantly 4x per block from L2 -> L2-BW-bound). 3-barrier loop:
// K(t+1) staged after S-phase (hides under softmax+PV); V(t+1) after PV.
// __launch_bounds__(256,2): the live set needs ~256 unified regs; min-3
// provably spills (R4/R5/R7: 84 VGPR + 400 MB scratch traffic).
// ---------------------------------------------------------------------------
#define BQ   128
#define BKEY 64

__global__ __launch_bounds__(256, 2)
void flash_kernel(const bf16* __restrict__ qh, const bf16* __restrict__ ql,
                  const bf16* __restrict__ khf, const bf16* __restrict__ klf,
                  const bf16* __restrict__ vtf,
                  bf16*  __restrict__ opart,   // [SPLIT][N][D_H] unnormalized
                  float* __restrict__ mpart,   // [SPLIT][N]
                  float* __restrict__ lpart)   // [SPLIT][N]
{
    __shared__ bf16 kh_s[BKEY * D_H];     // 16 KB, K-hi fragment order
    __shared__ bf16 kl_s[BKEY * D_H];     // 16 KB, K-lo
    __shared__ bf16 v_s[BKEY * D_H];      // 16 KB, V fragment order
    __shared__ bf16 p_s[4 * 2048];        // 16 KB, per-wave A-frag P

    const int t     = threadIdx.x;
    const int lane  = t & 63;
    const int wid   = t >> 6;
    const int lid   = lane & 15;
    const int quad  = lane >> 4;
    const int q0    = blockIdx.x * BQ;
    const int strip = wid * 32;
    const int sp    = blockIdx.y;
    const int tile0 = sp * (N_TOK / BKEY / SPLIT);     // 16 tiles per split
    const int tile1 = tile0 + (N_TOK / BKEY / SPLIT);

    bf16x8 a_hi[2][4], a_lo[2][4];
    #pragma unroll
    for (int m = 0; m < 2; ++m) {
        const size_t rowb = (size_t)(q0 + strip + m * 16 + lid) * D_H + quad * 8;
        #pragma unroll
        for (int kc = 0; kc < 4; ++kc) {
            a_hi[m][kc] = *(const bf16x8*)(qh + rowb + kc * 32);
            a_lo[m][kc] = *(const bf16x8*)(ql + rowb + kc * 32);
        }
    }

    bf16x8 vones;
    #pragma unroll
    for (int j = 0; j < 8; ++j) vones[j] = (bf16)1.0f;

    float m_run[2][4];
    #pragma unroll
    for (int m = 0; m < 2; ++m)
        #pragma unroll
        for (int r = 0; r < 4; ++r) m_run[m][r] = -INFINITY;
    floatx4 l_acc[2];
    #pragma unroll
    for (int m = 0; m < 2; ++m)
        #pragma unroll
        for (int r = 0; r < 4; ++r) l_acc[m][r] = 0.f;
    floatx4 o_acc[2][8];
    #pragma unroll
    for (int m = 0; m < 2; ++m)
        #pragma unroll
        for (int ct = 0; ct < 8; ++ct)
            #pragma unroll
            for (int r = 0; r < 4; ++r) o_acc[m][ct][r] = 0.f;

    // each wave stages its quarter (contiguous, lane-ordered)
    auto stage_k = [&](int tile) {
        const bf16* gh = khf + ((size_t)tile << 13) + (wid << 11) + (lane << 3);
        const bf16* gl = klf + ((size_t)tile << 13) + (wid << 11) + (lane << 3);
        bf16* lh = kh_s + (wid << 11);
        bf16* ll = kl_s + (wid << 11);
        #pragma unroll
        for (int i = 0; i < 4; ++i) {
            __builtin_amdgcn_global_load_lds(
                (const __attribute__((address_space(1))) void*)(gh + i * 512),
                (__attribute__((address_space(3))) void*)(lh + i * 512), 16, 0, 0);
            __builtin_amdgcn_global_load_lds(
                (const __attribute__((address_space(1))) void*)(gl + i * 512),
                (__attribute__((address_space(3))) void*)(ll + i * 512), 16, 0, 0);
        }
    };
    auto stage_v = [&](int tile) {
        const bf16* gv = vtf + ((size_t)tile << 13) + (wid << 11) + (lane << 3);
        bf16* lv = v_s + (wid << 11);
        #pragma unroll
        for (int i = 0; i < 4; ++i) {
            __builtin_amdgcn_global_load_lds(
                (const __attribute__((address_space(1))) void*)(gv + i * 512),
                (__attribute__((address_space(3))) void*)(lv + i * 512), 16, 0, 0);
        }
    };

    stage_k(tile0);
    stage_v(tile0);

    for (int tt = tile0; tt < tile1; ++tt) {
        __syncthreads();              // K(tt), V(tt) staged (vmcnt drained)

        // ---- S = (scaled q) . k^T : split-bf16 3-pass, 96 MFMA ----
        floatx4 s[2][4];
        #pragma unroll
        for (int m = 0; m < 2; ++m)
            #pragma unroll
            for (int ct = 0; ct < 4; ++ct)
                #pragma unroll
                for (int r = 0; r < 4; ++r) s[m][ct][r] = 0.f;

        #pragma unroll
        for (int kc = 0; kc < 4; ++kc)
            #pragma unroll
            for (int ct = 0; ct < 4; ++ct) {
                const int fo = ((kc * 4 + ct) << 9) + (lane << 3);
                bf16x8 bh = *(const bf16x8*)&kh_s[fo];
                bf16x8 bl = *(const bf16x8*)&kl_s[fo];
                #pragma unroll
                for (int m = 0; m < 2; ++m) {
                    s[m][ct] = MFMA16(a_hi[m][kc], bh, s[m][ct]);
                    s[m][ct] = MFMA16(a_lo[m][kc], bh, s[m][ct]);
                    s[m][ct] = MFMA16(a_hi[m][kc], bl, s[m][ct]);
                }
            }

        __syncthreads();              // all waves done reading K LDS
        if (tt + 1 < tile1) stage_k(tt + 1);   // hides under softmax + PV

        // ---- online softmax; P -> LDS in A-fragment order ----
        float alpha[2][4];
        #pragma unroll
        for (int m = 0; m < 2; ++m)
            #pragma unroll
            for (int r = 0; r < 4; ++r) {
                float mx = fmaxf(fmaxf(s[m][0][r], s[m][1][r]),
                                 fmaxf(s[m][2][r], s[m][3][r]));
                #pragma unroll
                for (int off = 1; off < 16; off <<= 1)
                    mx = fmaxf(mx, __shfl_xor(mx, off, 64));
                float mn = fmaxf(m_run[m][r], mx);
                alpha[m][r] = __expf(m_run[m][r] - mn);
                m_run[m][r] = mn;
                #pragma unroll
                for (int ct = 0; ct < 4; ++ct) {
                    float p = __expf(s[m][ct][r] - mn);
                    int fl = (((m * 2 + (ct >> 1)) << 6)
                              + (((ct & 1) * 2 + (lid >> 3)) << 4)
                              + quad * 4 + r) * 8 + (lid & 7);
                    p_s[(wid << 11) + fl] = (bf16)p;
                }
            }

        bool need = false;
        #pragma unroll
        for (int m = 0; m < 2; ++m)
            #pragma unroll
            for (int r = 0; r < 4; ++r) need |= (alpha[m][r] != 1.0f);
        if (__any(need)) {
            #pragma unroll
            for (int m = 0; m < 2; ++m) {
                #pragma unroll
                for (int r = 0; r < 4; ++r) l_acc[m][r] *= alpha[m][r];
                #pragma unroll
                for (int ct = 0; ct < 8; ++ct)
                    #pragma unroll
                    for (int r = 0; r < 4; ++r)
                        o_acc[m][ct][r] *= alpha[m][r];
            }
        }

        // ---- O += P V (V from LDS) ; l += P . 1 ----
        {
            bf16x8 ap0[2];
            #pragma unroll
            for (int m = 0; m < 2; ++m)
                ap0[m] = *(const bf16x8*)&p_s[(wid << 11) + ((m * 2 + 0) << 9)
                                              + (lane << 3)];
            #pragma unroll
            for (int m = 0; m < 2; ++m)
                l_acc[m] = MFMA16(ap0[m], vones, l_acc[m]);
            #pragma unroll
            for (int ct = 0; ct < 8; ++ct) {
                bf16x8 bv = *(const bf16x8*)&v_s[(ct << 10) + (lane << 3)];
                #pragma unroll
                for (int m = 0; m < 2; ++m)
                    o_acc[m][ct] = MFMA16(ap0[m], bv, o_acc[m][ct]);
            }

            bf16x8 ap1[2];
            #pragma unroll
            for (int m = 0; m < 2; ++m)
                ap1[m] = *(const bf16x8*)&p_s[(wid << 11) + ((m * 2 + 1) << 9)
                                              + (lane << 3)];
            #pragma unroll
            for (int m = 0; m < 2; ++m)
                l_acc[m] = MFMA16(ap1[m], vones, l_acc[m]);
            #pragma unroll
            for (int ct = 0; ct < 8; ++ct) {
                bf16x8 bv = *(const bf16x8*)&v_s[(ct << 10) + 512 + (lane << 3)];
                #pragma unroll
                for (int m = 0; m < 2; ++m)
                    o_acc[m][ct] = MFMA16(ap1[m], bv, o_acc[m][ct]);
            }
        }

        __syncthreads();              // all waves done reading V LDS
        if (tt + 1 < tile1) stage_v(tt + 1);
    }

    bf16* op = opart + (size_t)sp * N_TOK * D_H;
    #pragma unroll
    for (int m = 0; m < 2; ++m)
        #pragma unroll
        for (int ct = 0; ct < 8; ++ct)
            #pragma unroll
            for (int r = 0; r < 4; ++r)
                op[(size_t)(q0 + strip + m * 16 + quad * 4 + r) * D_H
                   + ct * 16 + lid] = (bf16)o_acc[m][ct][r];
    if (lid == 0) {
        #pragma unroll
        for (int m = 0; m < 2; ++m)
            #pragma unroll
            for (int r = 0; r < 4; ++r) {
                int row = q0 + strip + m * 16 + quad * 4 + r;
                mpart[(size_t)sp * N_TOK + row] = m_run[m][r];
                lpart[(size_t)sp * N_TOK + row] = l_acc[m][r];
            }
    }
}

// ---------------------------------------------------------------------------
// Kernel 3: merge the SPLIT partials.
// ---------------------------------------------------------------------------
__global__ __launch_bounds__(256)
void combine_kernel(const bf16* __restrict__ opart,
                    const float* __restrict__ mpart,
                    const float* __restrict__ lpart,
                    float* __restrict__ out)
{
    const int t   = threadIdx.x;
    const int row = blockIdx.x * 16 + (t >> 4);
    const int c0  = (t & 15) * 8;

    float ms[SPLIT], ls[SPLIT];
    float mstar = -INFINITY;
    #pragma unroll
    for (int s = 0; s < SPLIT; ++s) {
        ms[s] = mpart[(size_t)s * N_TOK + row];
        ls[s] = lpart[(size_t)s * N_TOK + row];
        mstar = fmaxf(mstar, ms[s]);
    }
    float acc[8] = {};
    float L = 0.f;
    #pragma unroll
    for (int s = 0; s < SPLIT; ++s) {
        float w = __expf(ms[s] - mstar);
        L += w * ls[s];
        bf16x8 o = *(const bf16x8*)&opart[((size_t)s * N_TOK + row) * D_H + c0];
        #pragma unroll
        for (int j = 0; j < 8; ++j)
            acc[j] += w * (float)o[j];
    }
    float inv = 1.f / L;
    float* dst = &out[(size_t)row * D_H + c0];
    *(float4*)(dst + 0) = make_float4(acc[0] * inv, acc[1] * inv,
                                      acc[2] * inv, acc[3] * inv);
    *(float4*)(dst + 4) = make_float4(acc[4] * inv, acc[5] * inv,
                                      acc[6] * inv, acc[7] * inv);
}

// ---------------------------------------------------------------------------
extern "C" void kernel_launch(void* const* d_in, const int* in_sizes, int n_in,
                              void* d_out, int out_size, void* d_ws, size_t ws_size,
                              hipStream_t stream) {
    const float* x  = (const float*)d_in[0];
    const float* Wq = (const float*)d_in[1];
    const float* Wk = (const float*)d_in[2];
    const float* Wv = (const float*)d_in[3];
    float* out = (float*)d_out;

    bf16* wsb = (bf16*)d_ws;
    const size_t SZ = (size_t)N_TOK * D_H;          // 1048576
    bf16* xhf = wsb;
    bf16* xlf = xhf + (size_t)X_OCT * 8;
    bf16* whf = xlf + (size_t)X_OCT * 8;
    bf16* wlf = whf + (size_t)W_OCT * 8;
    bf16* qh  = wlf + (size_t)W_OCT * 8;
    bf16* ql  = qh + SZ;
    bf16* khf = ql + SZ;
    bf16* klf = khf + SZ;
    bf16* vtf = klf + SZ;
    bf16* opart = vtf + SZ;
    float* mpart = (float*)(opart + (size_t)SPLIT * SZ);
    float* lpart = mpart + (size_t)SPLIT * N_TOK;

    convert_kernel<<<dim3((X_OCT + W_OCT) / 256), 256, 0, stream>>>(
        x, Wq, Wk, Wv, xhf, xlf, whf, wlf);
    qkv_kernel<<<dim3(N_TOK / 32, 3), 256, 0, stream>>>(
        xhf, xlf, whf, wlf, qh, ql, khf, klf, vtf);
    flash_kernel<<<dim3(N_TOK / BQ, SPLIT), 256, 0, stream>>>(
        qh, ql, khf, klf, vtf, opart, mpart, lpart);
    combine_kernel<<<dim3(N_TOK / 16), 256, 0, stream>>>(opart, mpart, lpart, out);
}

// Round 9
// 191.197 us; speedup vs baseline: 1.9485x; 1.2032x over previous
//
#include <hip/hip_runtime.h>
#include <hip/hip_bf16.h>
#include <math.h>
#include <stdint.h>

#define N_TOK 8192
#define D_IN  1024
#define D_H   128
#define SPLIT 8

typedef __bf16 bf16;
typedef __attribute__((ext_vector_type(4))) __bf16 bf16x4;
typedef __attribute__((ext_vector_type(8))) __bf16 bf16x8;
typedef __attribute__((ext_vector_type(4))) float floatx4;

#define MFMA16(a, b, c) __builtin_amdgcn_mfma_f32_16x16x32_bf16((a), (b), (c), 0, 0, 0)

// sqrt(128) * log2(e): softmax computed in exp2 domain (saves the ln2 mul in
// every __expf; combine_kernel uses exp2f to match).
#define QSCALE 16.322625246404958f

__device__ __forceinline__ uint32_t pack2(float a, float b) {
    union { bf16 h[2]; uint32_t u; } z;
    z.h[0] = (bf16)a; z.h[1] = (bf16)b; return z.u;
}

// V fragment order (A-frag of V^T == B-frag of V): [ntile][dt][lane][j]
__device__ __forceinline__ size_t vtf_idx(int n, int d) {
    return ((size_t)((n >> 6) * 8 + (d >> 4)) << 10)
         + (((n >> 3) & 7) << 7) + ((d & 15) << 3) + (n & 7);
}
// K fragment order (A-frag of K == B-frag of K^T): [ktile][kc][mt][lane][j]
__device__ __forceinline__ size_t khf_idx(int n, int d) {
    return ((size_t)(((n >> 6) * 4 + (d >> 5)) * 4 + ((n >> 4) & 3)) << 9)
         + (((d >> 3) & 3) << 7) + ((n & 15) << 3) + (d & 7);
}

#define X_OCT (N_TOK * D_IN / 8)
#define W_OCT (3 * D_H * D_IN / 8)

// ---------------------------------------------------------------------------
// Kernel 0: one-time fp32 -> split-bf16 conversion into MFMA fragment order.
// ---------------------------------------------------------------------------
__global__ __launch_bounds__(256)
void convert_kernel(const float* __restrict__ x,
                    const float* __restrict__ Wq,
                    const float* __restrict__ Wk,
                    const float* __restrict__ Wv,
                    bf16* __restrict__ xhf, bf16* __restrict__ xlf,
                    bf16* __restrict__ whf, bf16* __restrict__ wlf)
{
    const int gid = blockIdx.x * 256 + threadIdx.x;
    const float* src;
    bf16 *dh, *dl;
    size_t doff;
    if (gid < X_OCT) {
        int lane = gid & 63, fc = gid >> 6;
        int kc = fc & 31, mt = fc >> 5;
        int n  = mt * 16 + (lane & 15);
        int k0 = kc * 32 + ((lane >> 4) << 3);
        src = x + (size_t)n * D_IN + k0;
        dh = xhf; dl = xlf; doff = (size_t)gid << 3;
    } else {
        int w = gid - X_OCT;
        int y = w >> 14, r = w & 16383;
        int lane = r & 63, fc = r >> 6;
        int kc = fc & 31, ct = fc >> 5;
        int col = ct * 16 + (lane & 15);
        int k0  = kc * 32 + ((lane >> 4) << 3);
        const float* W = (y == 0) ? Wq : (y == 1) ? Wk : Wv;
        src = W + (size_t)col * D_IN + k0;
        dh = whf; dl = wlf; doff = (size_t)w << 3;
    }
    float4 a = *(const float4*)src;
    float4 b = *(const float4*)(src + 4);
    float vv[8] = { a.x, a.y, a.z, a.w, b.x, b.y, b.z, b.w };
    bf16x8 h, l;
    #pragma unroll
    for (int j = 0; j < 8; ++j) {
        bf16 hh = (bf16)vv[j];
        h[j] = hh;
        l[j] = (bf16)(vv[j] - (float)hh);
    }
    *(bf16x8*)(dh + doff) = h;
    *(bf16x8*)(dl + doff) = l;
}

// ---------------------------------------------------------------------------
// Kernel 1: QKV projection GEMM, split-bf16 3-pass MFMA.
// grid (128, 3), block 256 = 4 waves 2x2 (wr: 32-row half, wc: 64-col half).
// W fragments double-buffered in LDS via async global_load_lds (shared
// across waves -> kills the R8 W re-read problem); x frags direct global.
// Single barrier per K=64 chunk; staging overlaps the full chunk compute.
// ---------------------------------------------------------------------------
__global__ __launch_bounds__(256)
void qkv_kernel(const bf16* __restrict__ xhf, const bf16* __restrict__ xlf,
                const bf16* __restrict__ whf, const bf16* __restrict__ wlf,
                bf16* __restrict__ q_hi, bf16* __restrict__ q_lo,
                bf16* __restrict__ khf, bf16* __restrict__ klf,
                bf16* __restrict__ vtf)
{
    __shared__ bf16 w_s[2][16384];   // [buf][(hl*16 + ct*2 + kci)*512 + idx]

    const int t    = threadIdx.x;
    const int lane = t & 63;
    const int wid  = t >> 6;
    const int wr   = wid >> 1;
    const int wc   = wid & 1;
    const int lid  = lane & 15;
    const int quad = lane >> 4;
    const int m0   = blockIdx.x * 64;
    const bf16* wh = whf + ((size_t)blockIdx.y << 17);
    const bf16* wl = wlf + ((size_t)blockIdx.y << 17);

    auto stage = [&](int c0, int buf) {
        #pragma unroll
        for (int i = 0; i < 8; ++i) {
            int p   = wid * 8 + i;            // 0..31
            int hl  = p >> 4, ct = (p >> 1) & 7, kci = p & 1;
            const bf16* src = (hl ? wl : wh)
                            + ((size_t)(ct * 32 + c0 + kci) << 9) + (lane << 3);
            bf16* dst = &w_s[buf][p << 9];
            __builtin_amdgcn_global_load_lds(
                (const __attribute__((address_space(1))) void*)src,
                (__attribute__((address_space(3))) void*)dst, 16, 0, 0);
        }
    };

    floatx4 acc[2][4];
    #pragma unroll
    for (int m = 0; m < 2; ++m)
        #pragma unroll
        for (int ct = 0; ct < 4; ++ct)
            #pragma unroll
            for (int r = 0; r < 4; ++r) acc[m][ct][r] = 0.f;

    stage(0, 0);

    for (int c = 0; c < 16; ++c) {
        const int c0 = c * 2;
        const int cb = c & 1;
        __syncthreads();
        if (c < 15) stage(c0 + 2, cb ^ 1);

        #pragma unroll
        for (int kci = 0; kci < 2; ++kci) {
            bf16x8 ah[2], al[2];
            #pragma unroll
            for (int m = 0; m < 2; ++m) {
                int mt = (m0 >> 4) + wr * 2 + m;
                const size_t xb = ((size_t)(mt * 32 + c0 + kci) << 9) + (lane << 3);
                ah[m] = *(const bf16x8*)(xhf + xb);
                al[m] = *(const bf16x8*)(xlf + xb);
            }
            #pragma unroll
            for (int ct = 0; ct < 4; ++ct) {
                const int pb = (((wc * 4 + ct) * 2 + kci) << 9) + (lane << 3);
                bf16x8 bh = *(const bf16x8*)&w_s[cb][pb];
                bf16x8 bl = *(const bf16x8*)&w_s[cb][(16 << 9) + pb];
                #pragma unroll
                for (int m = 0; m < 2; ++m) {
                    acc[m][ct] = MFMA16(ah[m], bh, acc[m][ct]);
                    acc[m][ct] = MFMA16(al[m], bh, acc[m][ct]);
                    acc[m][ct] = MFMA16(ah[m], bl, acc[m][ct]);
                }
            }
        }
    }

    if (blockIdx.y == 0) {
        #pragma unroll
        for (int s2 = 0; s2 < 2; ++s2)
            #pragma unroll
            for (int ct = 0; ct < 4; ++ct)
                #pragma unroll
                for (int r = 0; r < 4; ++r) {
                    int row = m0 + wr * 32 + s2 * 16 + quad * 4 + r;
                    int col = wc * 64 + ct * 16 + lid;
                    float a = acc[s2][ct][r] * QSCALE;
                    bf16 h = (bf16)a;
                    q_hi[(size_t)row * D_H + col] = h;
                    q_lo[(size_t)row * D_H + col] = (bf16)(a - (float)h);
                }
    } else if (blockIdx.y == 1) {
        #pragma unroll
        for (int s2 = 0; s2 < 2; ++s2)
            #pragma unroll
            for (int ct = 0; ct < 4; ++ct)
                #pragma unroll
                for (int r = 0; r < 4; ++r) {
                    int n = m0 + wr * 32 + s2 * 16 + quad * 4 + r;
                    int d = wc * 64 + ct * 16 + lid;
                    float a = acc[s2][ct][r];
                    bf16 h = (bf16)a;
                    size_t idx = khf_idx(n, d);
                    khf[idx] = h;
                    klf[idx] = (bf16)(a - (float)h);
                }
    } else {
        #pragma unroll
        for (int s2 = 0; s2 < 2; ++s2)
            #pragma unroll
            for (int ct = 0; ct < 4; ++ct)
                #pragma unroll
                for (int r = 0; r < 4; ++r) {
                    int n = m0 + wr * 32 + s2 * 16 + quad * 4 + r;
                    int d = wc * 64 + ct * 16 + lid;
                    vtf[vtf_idx(n, d)] = (bf16)acc[s2][ct][r];
                }
    }
}

// ---------------------------------------------------------------------------
// Kernel 2: flash attention, TRANSPOSED formulation: S^T = K.Q^T (A=K frags
// from LDS, B=Q frags resident), O^T = V^T.P^T (A=V frags from global,
// B=P^T built IN-REGISTER from S^T's C-layout via lane shuffles — P never
// touches LDS, so the S->PV barrier is gone). K double-buffered in LDS,
// staged by async global_load_lds right after the single per-tile barrier
// (staging overlaps the whole tile's compute). Softmax max is in-lane over
// 16 keys + 2 shfl_xor. exp2-domain (scale pre-folded).
// grid (64, 8) = 512 blocks = 2 blocks/CU. LDS 64 KB. launch_bounds(256,2)
// (min-3 provably spills: R4/R5/R7).
// ---------------------------------------------------------------------------
#define BQ   128
#define BKEY 64

__global__ __launch_bounds__(256, 2)
void flash_kernel(const bf16* __restrict__ qh, const bf16* __restrict__ ql,
                  const bf16* __restrict__ khf, const bf16* __restrict__ klf,
                  const bf16* __restrict__ vtf,
                  bf16*  __restrict__ opart,   // [SPLIT][N][D_H] unnormalized
                  float* __restrict__ mpart,   // [SPLIT][N] (exp2 domain)
                  float* __restrict__ lpart)   // [SPLIT][N]
{
    __shared__ bf16 k_s[2][16384];   // [buf][ kh: 0..8191 | kl: 8192..16383 ]

    const int t     = threadIdx.x;
    const int lane  = t & 63;
    const int wid   = t >> 6;
    const int lid   = lane & 15;
    const int quad  = lane >> 4;
    const int q0    = blockIdx.x * BQ;
    const int strip = wid * 32;               // 32 q-rows per wave
    const int sp    = blockIdx.y;
    const int tile0 = sp * (N_TOK / BKEY / SPLIT);
    const int tile1 = tile0 + (N_TOK / BKEY / SPLIT);

    // Q as B-operand of Q^T: same loads as the old A-frags.
    bf16x8 b_hi[2][4], b_lo[2][4];            // [ct: qrow-tile][kc]
    #pragma unroll
    for (int ct = 0; ct < 2; ++ct) {
        const size_t rowb = (size_t)(q0 + strip + ct * 16 + lid) * D_H + quad * 8;
        #pragma unroll
        for (int kc = 0; kc < 4; ++kc) {
            b_hi[ct][kc] = *(const bf16x8*)(qh + rowb + kc * 32);
            b_lo[ct][kc] = *(const bf16x8*)(ql + rowb + kc * 32);
        }
    }

    bf16x8 vones;
    #pragma unroll
    for (int j = 0; j < 8; ++j) vones[j] = (bf16)1.0f;

    float m_run[2] = { -INFINITY, -INFINITY };   // per qrow-tile ct
    floatx4 l_acc[2];
    #pragma unroll
    for (int ct = 0; ct < 2; ++ct)
        #pragma unroll
        for (int r = 0; r < 4; ++r) l_acc[ct][r] = 0.f;
    floatx4 o_acc[8][2];                          // [dt][ct] = O^T frags
    #pragma unroll
    for (int dt = 0; dt < 8; ++dt)
        #pragma unroll
        for (int ct = 0; ct < 2; ++ct)
            #pragma unroll
            for (int r = 0; r < 4; ++r) o_acc[dt][ct][r] = 0.f;

    auto stage = [&](int tile, int buf) {
        const bf16* gh = khf + ((size_t)tile << 13) + (wid << 11) + (lane << 3);
        const bf16* gl = klf + ((size_t)tile << 13) + (wid << 11) + (lane << 3);
        bf16* lh = &k_s[buf][wid << 11];
        bf16* ll = lh + 8192;
        #pragma unroll
        for (int i = 0; i < 4; ++i) {
            __builtin_amdgcn_global_load_lds(
                (const __attribute__((address_space(1))) void*)(gh + i * 512),
                (__attribute__((address_space(3))) void*)(lh + i * 512), 16, 0, 0);
            __builtin_amdgcn_global_load_lds(
                (const __attribute__((address_space(1))) void*)(gl + i * 512),
                (__attribute__((address_space(3))) void*)(ll + i * 512), 16, 0, 0);
        }
    };

    stage(tile0, 0);

    for (int tt = tile0; tt < tile1; ++tt) {
        const int cb = (tt - tile0) & 1;
        __syncthreads();                      // buf cb staged; other buf free
        if (tt + 1 < tile1) stage(tt + 1, cb ^ 1);   // overlaps whole tile

        // ---- S^T = K . Q^T : split-bf16 3-pass, 96 MFMA ----
        const bf16* khp = &k_s[cb][0];
        const bf16* klp = &k_s[cb][8192];
        floatx4 s[4][2];                       // [mt: key-tile][ct: qrow-tile]
        #pragma unroll
        for (int mt = 0; mt < 4; ++mt)
            #pragma unroll
            for (int ct = 0; ct < 2; ++ct)
                #pragma unroll
                for (int r = 0; r < 4; ++r) s[mt][ct][r] = 0.f;

        #pragma unroll
        for (int kc = 0; kc < 4; ++kc)
            #pragma unroll
            for (int mt = 0; mt < 4; ++mt) {
                const int fo = ((kc * 4 + mt) << 9) + (lane << 3);
                bf16x8 ah = *(const bf16x8*)&khp[fo];
                bf16x8 al = *(const bf16x8*)&klp[fo];
                #pragma unroll
                for (int ct = 0; ct < 2; ++ct) {
                    s[mt][ct] = MFMA16(ah, b_hi[ct][kc], s[mt][ct]);
                    s[mt][ct] = MFMA16(al, b_hi[ct][kc], s[mt][ct]);
                    s[mt][ct] = MFMA16(ah, b_lo[ct][kc], s[mt][ct]);
                }
            }

        // ---- prefetch V kc2=0 A-frags (consumed after softmax) ----
        const bf16* vb = vtf + ((size_t)tt << 13) + (lane << 3);
        bf16x8 vf0[8];
        #pragma unroll
        for (int dt = 0; dt < 8; ++dt)
            vf0[dt] = *(const bf16x8*)(vb + ((size_t)dt << 10));

        // ---- softmax (exp2 domain): in-lane max over 16 keys + 2 shfl ----
        float alpha[2];
        uint32_t u0[4][2], u1[4][2];
        #pragma unroll
        for (int ct = 0; ct < 2; ++ct) {
            float mx = s[0][ct][0];
            #pragma unroll
            for (int mt = 0; mt < 4; ++mt)
                #pragma unroll
                for (int r = 0; r < 4; ++r)
                    mx = fmaxf(mx, s[mt][ct][r]);
            mx = fmaxf(mx, __shfl_xor(mx, 16, 64));
            mx = fmaxf(mx, __shfl_xor(mx, 32, 64));
            float mn = fmaxf(m_run[ct], mx);
            alpha[ct] = exp2f(m_run[ct] - mn);
            m_run[ct] = mn;
            #pragma unroll
            for (int mt = 0; mt < 4; ++mt) {
                float p0 = exp2f(s[mt][ct][0] - mn);
                float p1 = exp2f(s[mt][ct][1] - mn);
                float p2 = exp2f(s[mt][ct][2] - mn);
                float p3 = exp2f(s[mt][ct][3] - mn);
                u0[mt][ct] = pack2(p0, p1);
                u1[mt][ct] = pack2(p2, p3);
            }
        }

        // ---- build P^T B-frags in-register (lane permutation) ----
        // target lane (quad,lid), frag (kc2,ct), j=0..7 needs
        // P^T[key=kc2*32+quad*8+j][qrow=ct*16+lid]; source element lives in
        // lane (2*(quad&1) + (j>>2))*16+lid, s[kc2*2+(quad>>1)][ct] reg j&3.
        bf16x8 pB[2][2];
        {
            const int lsrc = ((quad & 1) << 5) + lid;
            const bool himt = (quad & 2) != 0;
            #pragma unroll
            for (int kc2 = 0; kc2 < 2; ++kc2)
                #pragma unroll
                for (int ct = 0; ct < 2; ++ct) {
                    const int mA = kc2 * 2, mB = kc2 * 2 + 1;
                    uint32_t w0a = __shfl((int)u0[mA][ct], lsrc, 64);
                    uint32_t w0b = __shfl((int)u0[mB][ct], lsrc, 64);
                    uint32_t w1a = __shfl((int)u1[mA][ct], lsrc, 64);
                    uint32_t w1b = __shfl((int)u1[mB][ct], lsrc, 64);
                    uint32_t w2a = __shfl((int)u0[mA][ct], lsrc + 16, 64);
                    uint32_t w2b = __shfl((int)u0[mB][ct], lsrc + 16, 64);
                    uint32_t w3a = __shfl((int)u1[mA][ct], lsrc + 16, 64);
                    uint32_t w3b = __shfl((int)u1[mB][ct], lsrc + 16, 64);
                    union { uint32_t w[4]; bf16x8 v; } z;
                    z.w[0] = himt ? w0b : w0a;
                    z.w[1] = himt ? w1b : w1a;
                    z.w[2] = himt ? w2b : w2a;
                    z.w[3] = himt ? w3b : w3a;
                    pB[kc2][ct] = z.v;
                }
        }

        // ---- prefetch V kc2=1 ----
        bf16x8 vf1[8];
        #pragma unroll
        for (int dt = 0; dt < 8; ++dt)
            vf1[dt] = *(const bf16x8*)(vb + ((size_t)dt << 10) + 512);

        // ---- rescale (skip when all alphas are 1) ----
        if (__any(alpha[0] != 1.0f || alpha[1] != 1.0f)) {
            #pragma unroll
            for (int ct = 0; ct < 2; ++ct) {
                #pragma unroll
                for (int r = 0; r < 4; ++r) l_acc[ct][r] *= alpha[ct];
                #pragma unroll
                for (int dt = 0; dt < 8; ++dt)
                    #pragma unroll
                    for (int r = 0; r < 4; ++r)
                        o_acc[dt][ct][r] *= alpha[ct];
            }
        }

        // ---- O^T += V^T P^T ; l += ones.P^T ----
        #pragma unroll
        for (int ct = 0; ct < 2; ++ct) {
            l_acc[ct] = MFMA16(vones, pB[0][ct], l_acc[ct]);
            l_acc[ct] = MFMA16(vones, pB[1][ct], l_acc[ct]);
        }
        #pragma unroll
        for (int dt = 0; dt < 8; ++dt)
            #pragma unroll
            for (int ct = 0; ct < 2; ++ct) {
                o_acc[dt][ct] = MFMA16(vf0[dt], pB[0][ct], o_acc[dt][ct]);
                o_acc[dt][ct] = MFMA16(vf1[dt], pB[1][ct], o_acc[dt][ct]);
            }
    }

    // ---- epilogue: O^T regs -> opart[qrow][d] (packed u32 stores) ----
    uint32_t* opw = (uint32_t*)(opart + (size_t)sp * N_TOK * D_H);
    #pragma unroll
    for (int dt = 0; dt < 8; ++dt)
        #pragma unroll
        for (int ct = 0; ct < 2; ++ct) {
            int qrow  = q0 + strip + ct * 16 + lid;
            int dbase = dt * 16 + quad * 4;
            opw[(qrow * D_H + dbase) >> 1]     = pack2(o_acc[dt][ct][0], o_acc[dt][ct][1]);
            opw[(qrow * D_H + dbase + 2) >> 1] = pack2(o_acc[dt][ct][2], o_acc[dt][ct][3]);
        }
    if (quad == 0) {
        #pragma unroll
        for (int ct = 0; ct < 2; ++ct) {
            int row = q0 + strip + ct * 16 + lid;
            mpart[(size_t)sp * N_TOK + row] = m_run[ct];
            lpart[(size_t)sp * N_TOK + row] = l_acc[ct][0];
        }
    }
}

// ---------------------------------------------------------------------------
// Kernel 3: merge the SPLIT partials (exp2 domain).
// ---------------------------------------------------------------------------
__global__ __launch_bounds__(256)
void combine_kernel(const bf16* __restrict__ opart,
                    const float* __restrict__ mpart,
                    const float* __restrict__ lpart,
                    float* __restrict__ out)
{
    const int t   = threadIdx.x;
    const int row = blockIdx.x * 16 + (t >> 4);
    const int c0  = (t & 15) * 8;

    float ms[SPLIT], ls[SPLIT];
    float mstar = -INFINITY;
    #pragma unroll
    for (int s = 0; s < SPLIT; ++s) {
        ms[s] = mpart[(size_t)s * N_TOK + row];
        ls[s] = lpart[(size_t)s * N_TOK + row];
        mstar = fmaxf(mstar, ms[s]);
    }
    float acc[8] = {};
    float L = 0.f;
    #pragma unroll
    for (int s = 0; s < SPLIT; ++s) {
        float w = exp2f(ms[s] - mstar);
        L += w * ls[s];
        bf16x8 o = *(const bf16x8*)&opart[((size_t)s * N_TOK + row) * D_H + c0];
        #pragma unroll
        for (int j = 0; j < 8; ++j)
            acc[j] += w * (float)o[j];
    }
    float inv = 1.f / L;
    float* dst = &out[(size_t)row * D_H + c0];
    *(float4*)(dst + 0) = make_float4(acc[0] * inv, acc[1] * inv,
                                      acc[2] * inv, acc[3] * inv);
    *(float4*)(dst + 4) = make_float4(acc[4] * inv, acc[5] * inv,
                                      acc[6] * inv, acc[7] * inv);
}

// ---------------------------------------------------------------------------
extern "C" void kernel_launch(void* const* d_in, const int* in_sizes, int n_in,
                              void* d_out, int out_size, void* d_ws, size_t ws_size,
                              hipStream_t stream) {
    const float* x  = (const float*)d_in[0];
    const float* Wq = (const float*)d_in[1];
    const float* Wk = (const float*)d_in[2];
    const float* Wv = (const float*)d_in[3];
    float* out = (float*)d_out;

    bf16* wsb = (bf16*)d_ws;
    const size_t SZ = (size_t)N_TOK * D_H;
    bf16* xhf = wsb;
    bf16* xlf = xhf + (size_t)X_OCT * 8;
    bf16* whf = xlf + (size_t)X_OCT * 8;
    bf16* wlf = whf + (size_t)W_OCT * 8;
    bf16* qh  = wlf + (size_t)W_OCT * 8;
    bf16* ql  = qh + SZ;
    bf16* khf = ql + SZ;
    bf16* klf = khf + SZ;
    bf16* vtf = klf + SZ;
    bf16* opart = vtf + SZ;
    float* mpart = (float*)(opart + (size_t)SPLIT * SZ);
    float* lpart = mpart + (size_t)SPLIT * N_TOK;

    convert_kernel<<<dim3((X_OCT + W_OCT) / 256), 256, 0, stream>>>(
        x, Wq, Wk, Wv, xhf, xlf, whf, wlf);
    qkv_kernel<<<dim3(N_TOK / 64, 3), 256, 0, stream>>>(
        xhf, xlf, whf, wlf, qh, ql, khf, klf, vtf);
    flash_kernel<<<dim3(N_TOK / BQ, SPLIT), 256, 0, stream>>>(
        qh, ql, khf, klf, vtf, opart, mpart, lpart);
    combine_kernel<<<dim3(N_TOK / 16), 256, 0, stream>>>(opart, mpart, lpart, out);
}